// Round 1
// baseline (286.553 us; speedup 1.0000x reference)
//
#include <hip/hip_runtime.h>
#include <math.h>

#define NUM_CLASSES 100000
#define EMB 512
#define BATCH 512
#define BN 64
#define NBLK ((NUM_CLASSES + BN - 1) / BN)   /* 1563 */
#define NPART (NBLK * 2)                     /* 3126 partials per row */

// ArcFace constants (margin m=0.3, scale s=120)
#define S_SCALE 120.0f
#define COS_M   0.9553364891256061f
#define SIN_M   0.29552020666133955f
#define TH_C   (-0.9553364891256061f)        /* cos(pi - m) */
#define MM_C    0.08865606199840187f         /* sin(pi - m) * m */

typedef short bf8 __attribute__((ext_vector_type(8)));   // 8 x bf16 (4 VGPRs)
typedef float f4  __attribute__((ext_vector_type(4)));   // MFMA accumulator

__device__ __forceinline__ unsigned short f2bf(float f) {
    union { float f; unsigned u; } a; a.f = f;
    unsigned r = a.u + 0x7fffu + ((a.u >> 16) & 1u);     // round-nearest-even
    return (unsigned short)(r >> 16);
}

// ---------------------------------------------------------------------------
// Kernel 1: L2-normalize rows of x (f32) -> bf16, one wave per row.
// ---------------------------------------------------------------------------
__global__ __launch_bounds__(256) void k_normx(const float* __restrict__ x,
                                               unsigned short* __restrict__ xb) {
    int row  = blockIdx.x * 4 + (threadIdx.x >> 6);
    int lane = threadIdx.x & 63;
    const float4* xr = (const float4*)(x + (size_t)row * EMB);
    float4 a = xr[lane * 2];
    float4 b = xr[lane * 2 + 1];
    float ss = a.x*a.x + a.y*a.y + a.z*a.z + a.w*a.w
             + b.x*b.x + b.y*b.y + b.z*b.z + b.w*b.w;
#pragma unroll
    for (int d = 1; d < 64; d <<= 1) ss += __shfl_xor(ss, d);
    float rn = 1.0f / fmaxf(sqrtf(ss), 1e-12f);
    int4 o;
    o.x = f2bf(a.x * rn) | (f2bf(a.y * rn) << 16);
    o.y = f2bf(a.z * rn) | (f2bf(a.w * rn) << 16);
    o.z = f2bf(b.x * rn) | (f2bf(b.y * rn) << 16);
    o.w = f2bf(b.z * rn) | (f2bf(b.w * rn) << 16);
    ((int4*)(xb + (size_t)row * EMB))[lane] = o;
}

// ---------------------------------------------------------------------------
// Main kernel: per block = 64 classes x ALL 512 batch rows.
//   stage W chunk f32->bf16 into swizzled LDS + per-class sumsq,
//   MFMA 16x16x32 bf16 GEMM, margin epilogue, online-softmax partials.
// Block: 512 threads = 8 waves = 4 M-bands (128 rows) x 2 N-halves (32 cls).
// ---------------------------------------------------------------------------
__global__ __launch_bounds__(512, 4) void k_main(
        const float* __restrict__ W, const unsigned short* __restrict__ xb,
        const long long* __restrict__ label, float2* __restrict__ pms,
        float* __restrict__ tgt) {
    __shared__ unsigned short Wl[BN * EMB];   // 64 KiB, rows XOR-swizzled
    __shared__ float ssq[BN];
    __shared__ int   lab[BATCH];

    const int tid = threadIdx.x;
    const int c0  = blockIdx.x * BN;

    if (tid < BN) ssq[tid] = 0.0f;
    lab[tid] = (int)label[tid];
    __syncthreads();

    // ---- stage: 64 classes x 512 f32 = 8192 float4, 16 per thread ----
#pragma unroll
    for (int i = 0; i < 16; ++i) {
        int lin = i * 512 + tid;
        int cc  = lin >> 7;        // class within chunk (all 128 stagers of a
        int kv  = lin & 127;       //  class are 2 consecutive waves)
        int c   = c0 + cc;
        float4 v = make_float4(0.f, 0.f, 0.f, 0.f);
        if (c < NUM_CLASSES) v = ((const float4*)W)[(size_t)c * (EMB / 4) + kv];
        float s = v.x*v.x + v.y*v.y + v.z*v.z + v.w*v.w;
        int boff = cc * 1024 + ((kv * 8) ^ ((cc & 7) << 4));   // swizzled
        *(uint2*)((char*)Wl + boff) =
            make_uint2(f2bf(v.x) | (f2bf(v.y) << 16), f2bf(v.z) | (f2bf(v.w) << 16));
#pragma unroll
        for (int d = 1; d < 64; d <<= 1) s += __shfl_xor(s, d);
        if ((tid & 63) == 0) atomicAdd(&ssq[cc], s);
    }
    __syncthreads();

    // ---- MFMA compute ----
    const int lane = tid & 63;
    const int wid  = tid >> 6;
    const int band = wid >> 1;   // M band: rows band*128 .. +128
    const int half = wid & 1;    // N half: classes half*32 .. +32
    const int l15  = lane & 15;
    const int lg   = lane >> 4;

    f4 acc[8][2];
#pragma unroll
    for (int mf = 0; mf < 8; ++mf)
#pragma unroll
        for (int nf = 0; nf < 2; ++nf)
#pragma unroll
            for (int i = 0; i < 4; ++i) acc[mf][nf][i] = 0.0f;

    const int rb0 = half * 32 + l15;       // B-frag class rows (within chunk)
    const int rb1 = rb0 + 16;
    const int sw  = (l15 & 7) << 4;        // same swizzle for rb0 & rb1
    const char* WlB = (const char*)Wl;
    const unsigned short* xp = xb + (size_t)(band * 128 + l15) * EMB;

    for (int k0 = 0; k0 < EMB; k0 += 32) {
        int kb = (k0 + lg * 8) * 2;        // byte offset of lane's 16B in a row
        bf8 b0 = *(const bf8*)(WlB + rb0 * 1024 + (kb ^ sw));
        bf8 b1 = *(const bf8*)(WlB + rb1 * 1024 + (kb ^ sw));
#pragma unroll
        for (int mf = 0; mf < 8; ++mf) {
            bf8 a = *(const bf8*)(xp + mf * 16 * EMB + k0 + lg * 8);
            acc[mf][0] = __builtin_amdgcn_mfma_f32_16x16x32_bf16(a, b0, acc[mf][0], 0, 0, 0);
            acc[mf][1] = __builtin_amdgcn_mfma_f32_16x16x32_bf16(a, b1, acc[mf][1], 0, 0, 0);
        }
    }

    // ---- epilogue: cosine -> margin -> online softmax partial ----
    float rn0 = 1.0f / fmaxf(sqrtf(ssq[half * 32 + l15]),      1e-12f);
    float rn1 = 1.0f / fmaxf(sqrtf(ssq[half * 32 + 16 + l15]), 1e-12f);
    const int cA = c0 + half * 32 + l15;
    const int cB = cA + 16;
    const int p  = blockIdx.x * 2 + half;

#pragma unroll
    for (int mf = 0; mf < 8; ++mf) {
        float v0a[4], v1a[4], mx[4], sm[4];
#pragma unroll
        for (int i = 0; i < 4; ++i) {
            int m  = band * 128 + mf * 16 + lg * 4 + i;   // C/D row mapping
            int lb = lab[m];
            float c0v = acc[mf][0][i] * rn0;
            float c1v = acc[mf][1][i] * rn1;
            float v0 = S_SCALE * c0v;
            float v1 = S_SCALE * c1v;
            if (cA == lb) {
                float sine = sqrtf(fmaxf(0.f, 1.f - c0v * c0v));
                float phi  = c0v * COS_M - sine * SIN_M;
                if (!(c0v > TH_C)) phi = c0v - MM_C;
                v0 = S_SCALE * phi;
                tgt[m] = v0;
            }
            if (cB == lb) {
                float sine = sqrtf(fmaxf(0.f, 1.f - c1v * c1v));
                float phi  = c1v * COS_M - sine * SIN_M;
                if (!(c1v > TH_C)) phi = c1v - MM_C;
                v1 = S_SCALE * phi;
                tgt[m] = v1;
            }
            if (cA >= NUM_CLASSES) v0 = -1e30f;   // tail-block padding
            if (cB >= NUM_CLASSES) v1 = -1e30f;
            v0a[i] = v0; v1a[i] = v1;
            mx[i] = fmaxf(v0, v1);
        }
#pragma unroll
        for (int d = 1; d < 16; d <<= 1)
#pragma unroll
            for (int i = 0; i < 4; ++i) mx[i] = fmaxf(mx[i], __shfl_xor(mx[i], d));
#pragma unroll
        for (int i = 0; i < 4; ++i)
            sm[i] = __expf(v0a[i] - mx[i]) + __expf(v1a[i] - mx[i]);
#pragma unroll
        for (int d = 1; d < 16; d <<= 1)
#pragma unroll
            for (int i = 0; i < 4; ++i) sm[i] += __shfl_xor(sm[i], d);
        if (l15 == 0) {
#pragma unroll
            for (int i = 0; i < 4; ++i) {
                int m = band * 128 + mf * 16 + lg * 4 + i;
                pms[(size_t)m * NPART + p] = make_float2(mx[i], sm[i]);
            }
        }
    }
}

// ---------------------------------------------------------------------------
// Kernel 3: merge 3126 (max,sum) partials per row -> loss[m] = LSE - tgt[m]
// ---------------------------------------------------------------------------
__global__ __launch_bounds__(256) void k_lse(const float2* __restrict__ pms,
                                             const float* __restrict__ tgt,
                                             float* __restrict__ loss) {
    int m = blockIdx.x, t = threadIdx.x;
    float M = -1e38f, Ssum = 0.f;
    for (int p = t; p < NPART; p += 256) {
        float2 v = pms[(size_t)m * NPART + p];
        float nM = fmaxf(M, v.x);
        Ssum = Ssum * __expf(M - nM) + v.y * __expf(v.x - nM);
        M = nM;
    }
#pragma unroll
    for (int d = 1; d < 64; d <<= 1) {
        float oM = __shfl_xor(M, d), oS = __shfl_xor(Ssum, d);
        float nM = fmaxf(M, oM);
        Ssum = Ssum * __expf(M - nM) + oS * __expf(oM - nM);
        M = nM;
    }
    __shared__ float2 wred[4];
    if ((t & 63) == 0) wred[t >> 6] = make_float2(M, Ssum);
    __syncthreads();
    if (t == 0) {
        M = wred[0].x; Ssum = wred[0].y;
        for (int w = 1; w < 4; ++w) {
            float oM = wred[w].x, oS = wred[w].y;
            float nM = fmaxf(M, oM);
            Ssum = Ssum * __expf(M - nM) + oS * __expf(oM - nM);
            M = nM;
        }
        loss[m] = M + logf(Ssum) - tgt[m];
    }
}

// ---------------------------------------------------------------------------
// Kernel 4: mean over 512 rows -> scalar
// ---------------------------------------------------------------------------
__global__ __launch_bounds__(512) void k_mean(const float* __restrict__ loss,
                                              float* __restrict__ out) {
    int t = threadIdx.x;
    float v = loss[t];
#pragma unroll
    for (int d = 1; d < 64; d <<= 1) v += __shfl_xor(v, d);
    __shared__ float wred[8];
    if ((t & 63) == 0) wred[t >> 6] = v;
    __syncthreads();
    if (t == 0) {
        float s = 0.f;
        for (int w = 0; w < 8; ++w) s += wred[w];
        out[0] = s / (float)BATCH;
    }
}

extern "C" void kernel_launch(void* const* d_in, const int* in_sizes, int n_in,
                              void* d_out, int out_size, void* d_ws, size_t ws_size,
                              hipStream_t stream) {
    const float*     x     = (const float*)d_in[0];
    const long long* label = (const long long*)d_in[1];
    const float*     W     = (const float*)d_in[2];
    float*           out   = (float*)d_out;

    // workspace layout (~12.8 MB total)
    char* ws = (char*)d_ws;
    unsigned short* xb  = (unsigned short*)ws;            // 512*512*2   = 524288 B
    float*          tgt = (float*)(ws + 524288);          // 512*4       = 2048 B
    float*          lss = (float*)(ws + 524288 + 2048);   // 512*4       = 2048 B
    float2*         pms = (float2*)(ws + 524288 + 4096);  // 512*3126*8  = 12804096 B

    k_normx<<<BATCH / 4, 256, 0, stream>>>(x, xb);
    k_main <<<NBLK,      512, 0, stream>>>(W, xb, label, pms, tgt);
    k_lse  <<<BATCH,     256, 0, stream>>>(pms, tgt, lss);
    k_mean <<<1,         512, 0, stream>>>(lss, out);
}